// Round 2
// baseline (735.504 us; speedup 1.0000x reference)
//
#include <hip/hip_runtime.h>
#include <hip/hip_bf16.h>
#include <stdint.h>

typedef unsigned short u16;
typedef __bf16 bf16x8 __attribute__((ext_vector_type(8)));
typedef unsigned short u16x8 __attribute__((ext_vector_type(8)));
typedef float f32x4 __attribute__((ext_vector_type(4)));

__device__ __forceinline__ float bf2f(u16 h) {
  union { uint32_t u; float f; } x;
  x.u = ((uint32_t)h) << 16;
  return x.f;
}
__device__ __forceinline__ u16 f2bf(float f) {
  union { float f; uint32_t u; } x;
  x.f = f;
  uint32_t r = x.u + 0x7FFFu + ((x.u >> 16) & 1u);  // round-to-nearest-even
  return (u16)(r >> 16);
}

// async global->LDS, 16B per lane. LDS dest must be wave-uniform base + lane*16.
__device__ __forceinline__ void gload_lds16(const u16* g, u16* l) {
  __builtin_amdgcn_global_load_lds(
      (const __attribute__((address_space(1))) uint32_t*)g,
      (__attribute__((address_space(3))) uint32_t*)l, 16, 0, 0);
}

// Inline-asm LDS read: opaque to the memory legalizer, so NO auto
// `s_waitcnt vmcnt(0)` is inserted against in-flight global_load_lds
// (that auto-drain is what killed the R1 pipeline). Completion is
// enforced manually via s_waitcnt lgkmcnt(0) + sched_barrier (rule #18).
typedef __attribute__((address_space(3))) const u16 lds_cu16;
__device__ __forceinline__ f32x4 ds_read128(const lds_cu16* p) {
  f32x4 r;
  asm volatile("ds_read_b128 %0, %1" : "=v"(r) : "v"(p));
  return r;
}

// One fused fp32->bf16 convert for x, W_qkv, W_o. Counts are 8-elem chunks.
__global__ __launch_bounds__(256) void cvt_all(
    const float* __restrict__ x, const float* __restrict__ w1,
    const float* __restrict__ w2, u16* __restrict__ xb,
    u16* __restrict__ w1b, u16* __restrict__ w2b, int n1, int n2, int n3) {
  int i = blockIdx.x * 256 + threadIdx.x;
  const float* src;
  u16* dst;
  int j = i;
  if (i < n1) { src = x; dst = xb; }
  else if (i < n1 + n2) { src = w1; dst = w1b; j = i - n1; }
  else if (i < n1 + n2 + n3) { src = w2; dst = w2b; j = i - n1 - n2; }
  else return;
  const float4* p = (const float4*)src + (size_t)j * 2;
  float4 a = p[0], b = p[1];
  u16x8 o;
  o[0] = f2bf(a.x); o[1] = f2bf(a.y); o[2] = f2bf(a.z); o[3] = f2bf(a.w);
  o[4] = f2bf(b.x); o[5] = f2bf(b.y); o[6] = f2bf(b.z); o[7] = f2bf(b.w);
  ((u16x8*)dst)[j] = o;
}

// ---------------------------------------------------------------------------
// OLD 128x128 gemm (m97 structure). Kept ONLY for PV (EPI=2). Proven correct.
// ---------------------------------------------------------------------------
template <typename OT, int EPI>
__global__ __launch_bounds__(256) void gemm_bt(
    const u16* __restrict__ A, int lda, long zsA,
    const u16* __restrict__ B, int ldb, long zsB,
    OT* __restrict__ C, int ldc, long zsC,
    int K, float scale, const float* __restrict__ rs) {
  const int z = blockIdx.z;
  A += (long)z * zsA;
  B += (long)z * zsB;
  C += (long)z * zsC;
  if constexpr (EPI == 2) rs += (long)z * 4096;

  __shared__ __align__(16) u16 As[2 * 128 * 32];
  __shared__ __align__(16) u16 Bs[2 * 128 * 32];
  const int tid  = threadIdx.x;
  const int m0   = blockIdx.y * 128;
  const int n0   = blockIdx.x * 128;
  const int wave = tid >> 6;
  const int lane = tid & 63;
  const int wm   = (wave >> 1) * 64;
  const int wn   = (wave & 1) * 64;
  const int l15  = lane & 15;
  const int quad = lane >> 4;

  f32x4 acc[4][4];
#pragma unroll
  for (int i = 0; i < 4; ++i)
#pragma unroll
    for (int j = 0; j < 4; ++j) acc[i][j] = f32x4{0.f, 0.f, 0.f, 0.f};

  const u16* gA0 = A + (size_t)(m0 + (tid >> 2)) * lda + (tid & 3) * 8;
  const u16* gA1 = A + (size_t)(m0 + 64 + (tid >> 2)) * lda + (tid & 3) * 8;
  const u16* gB0 = B + (size_t)(n0 + (tid >> 2)) * ldb + (tid & 3) * 8;
  const u16* gB1 = B + (size_t)(n0 + 64 + (tid >> 2)) * ldb + (tid & 3) * 8;
  u16* lA0 = As + tid * 8;
  u16* lA1 = As + (256 + tid) * 8;
  u16* lB0 = Bs + tid * 8;
  u16* lB1 = Bs + (256 + tid) * 8;

  for (int k0 = 0; k0 < K; k0 += 64) {
    __syncthreads();
#pragma unroll
    for (int s = 0; s < 2; ++s) {
      gload_lds16(gA0 + k0 + s * 32, lA0 + s * 4096);
      gload_lds16(gA1 + k0 + s * 32, lA1 + s * 4096);
      gload_lds16(gB0 + k0 + s * 32, lB0 + s * 4096);
      gload_lds16(gB1 + k0 + s * 32, lB1 + s * 4096);
    }
    __syncthreads();

#pragma unroll
    for (int s = 0; s < 2; ++s) {
      u16x8 a[4], b[4];
#pragma unroll
      for (int i = 0; i < 4; ++i)
        a[i] = *(const u16x8*)(As + s * 4096 + (wm + i * 16 + l15) * 32 + quad * 8);
#pragma unroll
      for (int j = 0; j < 4; ++j)
        b[j] = *(const u16x8*)(Bs + s * 4096 + (wn + j * 16 + l15) * 32 + quad * 8);
#pragma unroll
      for (int i = 0; i < 4; ++i)
#pragma unroll
        for (int j = 0; j < 4; ++j)
          acc[i][j] = __builtin_amdgcn_mfma_f32_16x16x32_bf16(
              __builtin_bit_cast(bf16x8, a[i]), __builtin_bit_cast(bf16x8, b[j]),
              acc[i][j], 0, 0, 0);
    }
  }

#pragma unroll
  for (int i = 0; i < 4; ++i) {
#pragma unroll
    for (int r = 0; r < 4; ++r) {
      const int row = m0 + wm + i * 16 + quad * 4 + r;
      float mul = scale;
      if constexpr (EPI == 2) mul = scale / rs[row];
      const size_t ro = (size_t)row * ldc;
#pragma unroll
      for (int j = 0; j < 4; ++j) {
        float v = acc[i][j][r] * mul;
        if constexpr (EPI == 1) v = __expf(v);
        const int col = n0 + wn + j * 16 + l15;
        if constexpr (__is_same(OT, float))
          C[ro + col] = v;
        else
          C[ro + col] = f2bf(v);
      }
    }
  }
}

// ---------------------------------------------------------------------------
// 256x256-tile 8-phase pipelined GEMM (m201 template, plain HIP).
// 512 thr = 8 waves (2M x 4N), per-wave C = 128x64 (acc[8][4]), BK=64.
// LDS: 2 K-tile buffers x 64 KiB = 128 KiB, st_16x32 XOR swizzle (R1: zero
// bank conflicts). global_load_lds writes linearly; swizzle is pre-applied
// to the per-lane GLOBAL k and re-applied on the ds_read address (rule #21).
//
// R2 change: fragment reads are inline-asm ds_read_b128 (invisible to the
// compiler's alias analysis -> no auto vmcnt(0) drain per phase), with manual
// `s_waitcnt lgkmcnt(0)` + sched_barrier(0) before each MFMA cluster
// (rule #18). vmcnt(4) only at ph4/ph8 -- never 0 in steady state.
//
// Liveness (per 2-K-tile iter; tiles t0=2i, t1=2i+1 in buf0/buf1):
//  - buf0 ds_reads happen only in ph1/ph2 and are lgkm-drained by each wave
//    before ph2's final barrier -> stages into buf0 at ph3-6 are WAR-safe.
//  - buf1 ds_reads only ph5/ph6, drained before ph6's final barrier ->
//    stages into buf1 at ph7,ph8,(next)ph1,ph2 are WAR-safe.
//  - WAITV(4) at ph4: outstanding = t1's 8 + t2's first 4; retires all of t1
//    before the barrier preceding ph5's reads.  WAITV(4) at ph8: retires all
//    of t2 before next-iter ph1 reads buf0. Last iter: WAITV(0) at ph4.
// ---------------------------------------------------------------------------
#define BAR() __builtin_amdgcn_s_barrier()
#define PRIO(n) __builtin_amdgcn_s_setprio(n)
#define WAITV(n) asm volatile("s_waitcnt vmcnt(" #n ")" ::: "memory")
#define WAITLGKM() asm volatile("s_waitcnt lgkmcnt(0)" ::: "memory")
#define SCHEDB() __builtin_amdgcn_sched_barrier(0)

#define STG(c, h, q, t)                                                         \
  gload_lds16(((h) < 2 ? gAs : gBs) +                                           \
                  (size_t)(((h) & 1) * 128 + (q) * 64) * ((h) < 2 ? lda : ldb) + \
                  (size_t)(t) * 64,                                             \
              lds + (c) * 32768 + ((h) < 2 ? 0 : 16384) +                       \
                  (((h) & 1) * 8 + (q) * 4) * 1024 + wsub * 512)

#define LDA_Q(c, qm)                                                            \
  {                                                                             \
    _Pragma("unroll") for (int ii = 0; ii < 4; ++ii) {                          \
      _Pragma("unroll") for (int kk = 0; kk < 2; ++kk)                          \
          a[(qm) * 4 + ii][kk] = ds_read128(Lp + (c) * 32768 +                  \
              ((wm8 + (qm) * 4 + ii) * 2 + kk) * 512 + rq);                     \
    }                                                                           \
  }

#define LDB_Q(c, qn)                                                            \
  {                                                                             \
    _Pragma("unroll") for (int jj = 0; jj < 2; ++jj) {                          \
      _Pragma("unroll") for (int kk = 0; kk < 2; ++kk)                          \
          b[(qn) * 2 + jj][kk] = ds_read128(Lp + (c) * 32768 + 16384 +          \
              ((wn4 + (qn) * 2 + jj) * 2 + kk) * 512 + rq);                     \
    }                                                                           \
  }

#define MFMA_Q(qm, qn)                                                          \
  {                                                                             \
    PRIO(1);                                                                    \
    _Pragma("unroll") for (int kk = 0; kk < 2; ++kk) {                          \
      _Pragma("unroll") for (int ii = 0; ii < 4; ++ii) {                        \
        _Pragma("unroll") for (int jj = 0; jj < 2; ++jj)                        \
            acc[(qm) * 4 + ii][(qn) * 2 + jj] =                                 \
                __builtin_amdgcn_mfma_f32_16x16x32_bf16(                        \
                    __builtin_bit_cast(bf16x8, a[(qm) * 4 + ii][kk]),           \
                    __builtin_bit_cast(bf16x8, b[(qn) * 2 + jj][kk]),           \
                    acc[(qm) * 4 + ii][(qn) * 2 + jj], 0, 0, 0);                \
      }                                                                         \
    }                                                                           \
    PRIO(0);                                                                    \
    SCHEDB();                                                                   \
  }

template <typename OT, int EPI>
__global__ __launch_bounds__(512, 2) void gemm256(
    const u16* __restrict__ A, int lda, long zsA,
    const u16* __restrict__ B, int ldb, long zsB,
    OT* __restrict__ C, int ldc, long zsC,
    int K, float scale, const float* __restrict__ rs) {
  __shared__ __align__(16) u16 lds[65536];  // 128 KiB: [buf][A|B][16 rb][2 kb][512]
  const int z = blockIdx.z;
  A += (long)z * zsA;
  B += (long)z * zsB;
  C += (long)z * zsC;
  if constexpr (EPI == 2) rs += (long)z * 4096;

  const int tid  = threadIdx.x;
  const int lane = tid & 63;
  const int w    = tid >> 6;    // wave 0..7
  const int wm   = w >> 2;      // 0..1  (M)
  const int wn   = w & 3;       // 0..3  (N)
  const int wm8  = wm * 8;
  const int wn4  = wn * 4;
  const int l15  = lane & 15;
  const int quad = lane >> 4;
  const int m0   = blockIdx.y * 256;
  const int n0   = blockIdx.x * 256;

  // Staging geometry (R1-verified, zero bank conflicts): wave w owns subtile
  // (rowblock w>>1, kblock w&1); lane l -> row l>>2, k (l&3)*8, with the k
  // pre-XOR implementing the st_16x32 swizzle for rows >= 8 of each 16-row
  // subtile (byte ^= ((byte>>9)&1)<<5).
  const int srow = (w >> 1) * 16 + (lane >> 2);
  const int kcol = ((lane & 3) * 8) ^ ((lane & 32) ? 16 : 0);
  const int skb  = w & 1;
  const u16* gAs = A + (size_t)(m0 + srow) * lda + skb * 32 + kcol;
  const u16* gBs = B + (size_t)(n0 + srow) * ldb + skb * 32 + kcol;
  const int wsub = (w >> 1) * 2 + skb;

  // Fragment read offset within a subtile (u16 units), same swizzle.
  const int rq = (l15 * 32 + quad * 8) ^ ((l15 & 8) << 1);
  const lds_cu16* Lp = (const lds_cu16*)lds;

  f32x4 acc[8][4];
#pragma unroll
  for (int i = 0; i < 8; ++i)
#pragma unroll
    for (int j = 0; j < 4; ++j) acc[i][j] = f32x4{0.f, 0.f, 0.f, 0.f};
  f32x4 a[8][2], b[4][2];

  const int ni = K >> 7;  // iterations of 2 K-tiles (K % 128 == 0)

  // Prologue: tile0 -> buf0 fully; tile1 -> buf1 halves h0,h1. 12 loads;
  // WAITV(4): t0's 8 loads retired, t1's 4 stay in flight.
#pragma unroll
  for (int h = 0; h < 4; ++h) { STG(0, h, 0, 0); STG(0, h, 1, 0); }
  STG(1, 0, 0, 1); STG(1, 0, 1, 1);
  STG(1, 1, 0, 1); STG(1, 1, 1, 1);
  WAITV(4);
  BAR();

  for (int i = 0; i < ni; ++i) {
    const int t1 = 2 * i + 1, t2 = 2 * i + 2, t3 = 2 * i + 3;
    const bool more = (i + 1 < ni);

    // ph1: read buf0 {aq0, bq0} | stage buf1.h2(t1) | MFMA Q00
    LDA_Q(0, 0); LDB_Q(0, 0);
    STG(1, 2, 0, t1); STG(1, 2, 1, t1);
    BAR(); WAITLGKM(); SCHEDB();
    MFMA_Q(0, 0); BAR();
    // ph2: read buf0 {aq1, bq1} | stage buf1.h3(t1) | MFMA Q01
    LDA_Q(0, 1); LDB_Q(0, 1);
    STG(1, 3, 0, t1); STG(1, 3, 1, t1);
    BAR(); WAITLGKM(); SCHEDB();
    MFMA_Q(0, 1); BAR();
    // ph3: stage buf0.h0(t2) | MFMA Q10 (regs from ph2)
    if (more) { STG(0, 0, 0, t2); STG(0, 0, 1, t2); }
    BAR(); SCHEDB();
    MFMA_Q(1, 0); BAR();
    // ph4: stage buf0.h1(t2) | vmcnt(4) -> all of t1 landed | MFMA Q11
    if (more) { STG(0, 1, 0, t2); STG(0, 1, 1, t2); WAITV(4); }
    else { WAITV(0); }
    BAR(); SCHEDB();
    MFMA_Q(1, 1); BAR();
    // ph5: read buf1 {aq0, bq0} | stage buf0.h2(t2) | MFMA Q00
    LDA_Q(1, 0); LDB_Q(1, 0);
    if (more) { STG(0, 2, 0, t2); STG(0, 2, 1, t2); }
    BAR(); WAITLGKM(); SCHEDB();
    MFMA_Q(0, 0); BAR();
    // ph6: read buf1 {aq1, bq1} | stage buf0.h3(t2) | MFMA Q01
    LDA_Q(1, 1); LDB_Q(1, 1);
    if (more) { STG(0, 3, 0, t2); STG(0, 3, 1, t2); }
    BAR(); WAITLGKM(); SCHEDB();
    MFMA_Q(0, 1); BAR();
    // ph7: stage buf1.h0(t3) | MFMA Q10
    if (more) { STG(1, 0, 0, t3); STG(1, 0, 1, t3); }
    BAR(); SCHEDB();
    MFMA_Q(1, 0); BAR();
    // ph8: stage buf1.h1(t3) | vmcnt(4) -> all of t2 landed | MFMA Q11
    if (more) { STG(1, 1, 0, t3); STG(1, 1, 1, t3); WAITV(4); }
    BAR(); SCHEDB();
    MFMA_Q(1, 1); BAR();
  }

  // Epilogue. C/D layout (m89-verified): col = lane&15, row = (lane>>4)*4 + reg
#pragma unroll
  for (int i = 0; i < 8; ++i) {
#pragma unroll
    for (int r = 0; r < 4; ++r) {
      const int row = m0 + wm * 128 + i * 16 + quad * 4 + r;
      float mul = scale;
      if constexpr (EPI == 2) mul = scale / rs[row];
      const size_t ro = (size_t)row * ldc;
#pragma unroll
      for (int j = 0; j < 4; ++j) {
        float v = acc[i][j][r] * mul;
        if constexpr (EPI == 1) v = __expf(v);
        const int col = n0 + wn * 64 + j * 16 + l15;
        if constexpr (__is_same(OT, float))
          C[ro + col] = v;
        else
          C[ro + col] = f2bf(v);
      }
    }
  }
}

// rs[z*4096+row] = sum over 4096 cols of P[z][row][*] (bf16). Direct write.
__global__ __launch_bounds__(256) void rowsum_rows(
    const u16* __restrict__ P, long zsP, float* __restrict__ rs) {
  const int row = blockIdx.x;
  const int z   = blockIdx.y;
  const u16* p = P + (long)z * zsP + (size_t)row * 4096;
  const int tid  = threadIdx.x;
  const int lane = tid & 63;
  const int wave = tid >> 6;

  u16x8 h0 = *(const u16x8*)(p + tid * 16);
  u16x8 h1 = *(const u16x8*)(p + tid * 16 + 8);
  float s = 0.f;
#pragma unroll
  for (int j = 0; j < 8; ++j) s += bf2f(h0[j]) + bf2f(h1[j]);
  for (int o = 32; o > 0; o >>= 1) s += __shfl_xor(s, o, 64);
  __shared__ float red[4];
  if (lane == 0) red[wave] = s;
  __syncthreads();
  if (tid == 0) rs[(size_t)z * 4096 + row] = red[0] + red[1] + red[2] + red[3];
}

// Vt[z][d, s] = V[z][s, d].
__global__ __launch_bounds__(256) void transpose_v(
    const u16* __restrict__ V, int ldv, long zsV,
    u16* __restrict__ Vt, int ldt, long zsT) {
  const int z = blockIdx.z;
  V  += (long)z * zsV;
  Vt += (long)z * zsT;
  __shared__ u16 T[64][65];
  const int d0 = blockIdx.x * 64;
  const int s0 = blockIdx.y * 64;
  const int tid = threadIdx.x;
  const int c = tid & 63;
  const int rbase = (tid >> 6) * 16;
#pragma unroll
  for (int r = 0; r < 16; ++r)
    T[rbase + r][c] = V[(size_t)(s0 + rbase + r) * ldv + d0 + c];
  __syncthreads();
#pragma unroll
  for (int r = 0; r < 16; ++r)
    Vt[(size_t)(d0 + rbase + r) * ldt + s0 + c] = T[c][rbase + r];
}

extern "C" void kernel_launch(void* const* d_in, const int* in_sizes, int n_in,
                              void* d_out, int out_size, void* d_ws, size_t ws_size,
                              hipStream_t stream) {
  const float* x    = (const float*)d_in[0];  // [B*S, D] fp32
  const float* Wqkv = (const float*)d_in[1];  // [3D, D]  fp32
  const float* Wo   = (const float*)d_in[2];  // [D, D]   fp32
  float* out = (float*)d_out;                 // [B*S, D] fp32

  const int Bn = 4, S = 4096, D = 1024;
  const int M = Bn * S;  // 16384
  const int E = 3 * D;   // 3072
  const long SE = (long)S * E, SS = (long)S * S, DS = (long)D * S, SD = (long)S * D;

  const int nz = (ws_size >= (size_t)226492416) ? 2 : 1;  // 216 MB

  char* ws = (char*)d_ws;
  size_t off = 0;
  u16* qkv = (u16*)(ws + off);  off += (size_t)M * E * 2;        // 96 MB
  u16* Sb  = (u16*)(ws + off);  off += (size_t)nz * S * S * 2;   // nz*32 MB
  u16* Vt  = (u16*)(ws + off);  off += (size_t)nz * D * S * 2;   // nz*8 MB
  u16* xb  = (u16*)(ws + off);  off += (size_t)M * D * 2;        // 32 MB
  u16* attn = xb;                 // xb dead after QKV proj
  u16* Wqkvb = (u16*)(ws + off); off += (size_t)E * D * 2;       // 6 MB
  u16* Wob   = (u16*)(ws + off); off += (size_t)D * D * 2;       // 2 MB
  float* rs = (float*)Wqkvb;      // aliases Wqkvb (dead after QKV gemm)

  // 0) fp32 -> bf16 converts (fused)
  const int n1 = M * D / 8, n2 = E * D / 8, n3 = D * D / 8;
  cvt_all<<<(n1 + n2 + n3 + 255) / 256, 256, 0, stream>>>(
      x, Wqkv, Wo, xb, Wqkvb, Wob, n1, n2, n3);

  // 1) QKV projection: qkv = xb @ Wqkvb^T   [16384 x 3072], 12x64 = 768 blocks
  gemm256<u16, 0><<<dim3(E / 256, M / 256, 1), 512, 0, stream>>>(
      xb, D, 0, Wqkvb, D, 0, qkv, E, 0, D, 1.0f, nullptr);

  const float scl = 0.03125f;  // 1/sqrt(1024)
  for (int c = 0; c < Bn; c += nz) {
    const u16* Qc = qkv + (size_t)c * SE;
    transpose_v<<<dim3(D / 64, S / 64, nz), 256, 0, stream>>>(
        Qc + 2 * D, E, SE, Vt, S, DS);
    // QK^T with exp epilogue: 16x16xnz blocks (512 @ nz=2)
    gemm256<u16, 1><<<dim3(S / 256, S / 256, nz), 512, 0, stream>>>(
        Qc, E, SE, Qc + D, E, SE, Sb, S, SS, D, scl, nullptr);
    rowsum_rows<<<dim3(S, nz), 256, 0, stream>>>(Sb, SS, rs);
    // PV stays on 128^2 kernel: 256-tile grid would be only 128 blocks.
    gemm_bt<u16, 2><<<dim3(D / 128, S / 128, nz), 256, 0, stream>>>(
        Sb, S, SS, Vt, S, DS, attn + (size_t)c * SD, D, SD, S, 1.0f, rs);
  }

  // 2) out = attn @ Wo^T  [16384 x 1024] -> fp32, 4x64 = 256 blocks
  gemm256<float, 0><<<dim3(D / 256, M / 256, 1), 512, 0, stream>>>(
      attn, D, 0, Wob, D, 0, out, D, 0, D, 1.0f, nullptr);
}

// Round 4
// 629.790 us; speedup vs baseline: 1.1679x; 1.1679x over previous
//
#include <hip/hip_runtime.h>
#include <hip/hip_bf16.h>
#include <stdint.h>

typedef unsigned short u16;
typedef __bf16 bf16x8 __attribute__((ext_vector_type(8)));
typedef unsigned short u16x8 __attribute__((ext_vector_type(8)));
typedef float f32x4 __attribute__((ext_vector_type(4)));

__device__ __forceinline__ float bf2f(u16 h) {
  union { uint32_t u; float f; } x;
  x.u = ((uint32_t)h) << 16;
  return x.f;
}
__device__ __forceinline__ u16 f2bf(float f) {
  union { float f; uint32_t u; } x;
  x.f = f;
  uint32_t r = x.u + 0x7FFFu + ((x.u >> 16) & 1u);  // round-to-nearest-even
  return (u16)(r >> 16);
}

// async global->LDS, 16B per lane. LDS dest must be wave-uniform base + lane*16.
__device__ __forceinline__ void gload_lds16(const u16* g, u16* l) {
  __builtin_amdgcn_global_load_lds(
      (const __attribute__((address_space(1))) uint32_t*)g,
      (__attribute__((address_space(3))) uint32_t*)l, 16, 0, 0);
}

// Inline-asm LDS read with compile-time byte offset immediate. Opaque to the
// memory legalizer -> no auto vmcnt(0) drain against in-flight
// global_load_lds. Must stay volatile: non-volatile would allow CSE/hoist of
// re-reads across staging barriers (race). Completion via s_waitcnt
// lgkmcnt(0) + sched_barrier(0) (rule #18). No "memory" clobbers (R2 lesson).
typedef __attribute__((address_space(3))) const u16 lds_cu16;
template <int OFF>
__device__ __forceinline__ f32x4 ds_read128o(const lds_cu16* p) {
  f32x4 r;
  asm volatile("ds_read_b128 %0, %1 offset:%2" : "=v"(r) : "v"(p), "n"(OFF));
  return r;
}

// One fused fp32->bf16 convert for x, W_qkv, W_o. Counts are 8-elem chunks.
__global__ __launch_bounds__(256) void cvt_all(
    const float* __restrict__ x, const float* __restrict__ w1,
    const float* __restrict__ w2, u16* __restrict__ xb,
    u16* __restrict__ w1b, u16* __restrict__ w2b, int n1, int n2, int n3) {
  int i = blockIdx.x * 256 + threadIdx.x;
  const float* src;
  u16* dst;
  int j = i;
  if (i < n1) { src = x; dst = xb; }
  else if (i < n1 + n2) { src = w1; dst = w1b; j = i - n1; }
  else if (i < n1 + n2 + n3) { src = w2; dst = w2b; j = i - n1 - n2; }
  else return;
  const float4* p = (const float4*)src + (size_t)j * 2;
  float4 a = p[0], b = p[1];
  u16x8 o;
  o[0] = f2bf(a.x); o[1] = f2bf(a.y); o[2] = f2bf(a.z); o[3] = f2bf(a.w);
  o[4] = f2bf(b.x); o[5] = f2bf(b.y); o[6] = f2bf(b.z); o[7] = f2bf(b.w);
  ((u16x8*)dst)[j] = o;
}

// ---------------------------------------------------------------------------
// OLD 128x128 gemm (m97 structure). Kept ONLY for PV (EPI=2). Proven correct.
// ---------------------------------------------------------------------------
template <typename OT, int EPI>
__global__ __launch_bounds__(256) void gemm_bt(
    const u16* __restrict__ A, int lda, long zsA,
    const u16* __restrict__ B, int ldb, long zsB,
    OT* __restrict__ C, int ldc, long zsC,
    int K, float scale, const float* __restrict__ rs) {
  const int z = blockIdx.z;
  A += (long)z * zsA;
  B += (long)z * zsB;
  C += (long)z * zsC;
  if constexpr (EPI == 2) rs += (long)z * 4096;

  __shared__ __align__(16) u16 As[2 * 128 * 32];
  __shared__ __align__(16) u16 Bs[2 * 128 * 32];
  const int tid  = threadIdx.x;
  const int m0   = blockIdx.y * 128;
  const int n0   = blockIdx.x * 128;
  const int wave = tid >> 6;
  const int lane = tid & 63;
  const int wm   = (wave >> 1) * 64;
  const int wn   = (wave & 1) * 64;
  const int l15  = lane & 15;
  const int quad = lane >> 4;

  f32x4 acc[4][4];
#pragma unroll
  for (int i = 0; i < 4; ++i)
#pragma unroll
    for (int j = 0; j < 4; ++j) acc[i][j] = f32x4{0.f, 0.f, 0.f, 0.f};

  const u16* gA0 = A + (size_t)(m0 + (tid >> 2)) * lda + (tid & 3) * 8;
  const u16* gA1 = A + (size_t)(m0 + 64 + (tid >> 2)) * lda + (tid & 3) * 8;
  const u16* gB0 = B + (size_t)(n0 + (tid >> 2)) * ldb + (tid & 3) * 8;
  const u16* gB1 = B + (size_t)(n0 + 64 + (tid >> 2)) * ldb + (tid & 3) * 8;
  u16* lA0 = As + tid * 8;
  u16* lA1 = As + (256 + tid) * 8;
  u16* lB0 = Bs + tid * 8;
  u16* lB1 = Bs + (256 + tid) * 8;

  for (int k0 = 0; k0 < K; k0 += 64) {
    __syncthreads();
#pragma unroll
    for (int s = 0; s < 2; ++s) {
      gload_lds16(gA0 + k0 + s * 32, lA0 + s * 4096);
      gload_lds16(gA1 + k0 + s * 32, lA1 + s * 4096);
      gload_lds16(gB0 + k0 + s * 32, lB0 + s * 4096);
      gload_lds16(gB1 + k0 + s * 32, lB1 + s * 4096);
    }
    __syncthreads();

#pragma unroll
    for (int s = 0; s < 2; ++s) {
      u16x8 a[4], b[4];
#pragma unroll
      for (int i = 0; i < 4; ++i)
        a[i] = *(const u16x8*)(As + s * 4096 + (wm + i * 16 + l15) * 32 + quad * 8);
#pragma unroll
      for (int j = 0; j < 4; ++j)
        b[j] = *(const u16x8*)(Bs + s * 4096 + (wn + j * 16 + l15) * 32 + quad * 8);
#pragma unroll
      for (int i = 0; i < 4; ++i)
#pragma unroll
        for (int j = 0; j < 4; ++j)
          acc[i][j] = __builtin_amdgcn_mfma_f32_16x16x32_bf16(
              __builtin_bit_cast(bf16x8, a[i]), __builtin_bit_cast(bf16x8, b[j]),
              acc[i][j], 0, 0, 0);
    }
  }

#pragma unroll
  for (int i = 0; i < 4; ++i) {
#pragma unroll
    for (int r = 0; r < 4; ++r) {
      const int row = m0 + wm + i * 16 + quad * 4 + r;
      float mul = scale;
      if constexpr (EPI == 2) mul = scale / rs[row];
      const size_t ro = (size_t)row * ldc;
#pragma unroll
      for (int j = 0; j < 4; ++j) {
        float v = acc[i][j][r] * mul;
        if constexpr (EPI == 1) v = __expf(v);
        const int col = n0 + wn + j * 16 + l15;
        if constexpr (__is_same(OT, float))
          C[ro + col] = v;
        else
          C[ro + col] = f2bf(v);
      }
    }
  }
}

// ---------------------------------------------------------------------------
// 256x256-tile 8-phase pipelined GEMM (R4: race-free per-phase-read schedule).
// 512 thr = 8 waves (2M x 4N), per-wave C = 128x64 (acc[8][4]), BK=64.
// LDS 128 KiB = 2 K-tile bufs, st_16x32 XOR swizzle (verified 0 conflicts).
//
// Buffer ownership (iter i, tiles t0=2i in buf0, t1=2i+1 in buf1):
//   reads:  ph1-4 read buf0 only; ph5-8 read buf1 only.
//   stages: ph1-2 stage t1 -> buf1 (4 calls each, full tile);
//           ph5-6 stage t2=2i+2 -> buf0 (gated by `more`).
//   waits:  vmcnt(0) ONLY at end of ph4 / ph8, after the MFMA cluster and
//           before the closing barrier; the drained loads have a 2-3 phase
//           lead (~2.5k cyc >> 900-cyc HBM) so the wait is ~free.
// Safety:
//   RAW ph1 (buf0): t0/t2 staged in prev ph5-6, drained at prev ph8 vmcnt(0),
//     barrier-ordered before ph1's ds_reads.  RAW ph5 (buf1): t1 staged
//     ph1-2, drained at ph4 vmcnt(0) + barrier.
//   WAR ph1-2 writes buf1: all buf1 reads were prev ph5-8, each wave drained
//     them (lgkmcnt(0)) before its MFMA; ph8's end barrier orders the writes
//     after.  WAR ph5-6 writes buf0: buf0 reads end at ph4 (same argument).
//   In-phase: reads and stages always target DIFFERENT buffers (R3's bug was
//     ph3/4 staging the buffer being read).
// ---------------------------------------------------------------------------
#define BAR() __builtin_amdgcn_s_barrier()
#define PRIO(n) __builtin_amdgcn_s_setprio(n)
#define WAITV(n) asm volatile("s_waitcnt vmcnt(" #n ")")
#define WAITLGKM() asm volatile("s_waitcnt lgkmcnt(0)")
#define SCHEDB() __builtin_amdgcn_sched_barrier(0)
#define DSR(p, off) ds_read128o<(off)>(p)
#define AO(qm, ii, kk) ((((qm) * 4 + (ii)) * 2 + (kk)) * 1024)
#define BO(qn, jj, kk) ((((qn) * 2 + (jj)) * 2 + (kk)) * 1024)

#define STG(c, h, q, t)                                                         \
  gload_lds16(((h) < 2 ? gAs : gBs) +                                           \
                  (size_t)(((h) & 1) * 128 + (q) * 64) * ((h) < 2 ? lda : ldb) + \
                  (size_t)(t) * 64,                                             \
              lds + (c) * 32768 + ((h) < 2 ? 0 : 16384) +                       \
                  (((h) & 1) * 8 + (q) * 4) * 1024 + wsub * 512)

#define MM(qm, ii, qn, jj, AV, BV)                                              \
  acc[(qm) * 4 + (ii)][(qn) * 2 + (jj)] =                                       \
      __builtin_amdgcn_mfma_f32_16x16x32_bf16(                                  \
          __builtin_bit_cast(bf16x8, AV), __builtin_bit_cast(bf16x8, BV),       \
          acc[(qm) * 4 + (ii)][(qn) * 2 + (jj)], 0, 0, 0);

#define PH(LA, LB, qm, qn, STGS, TAILW)                                         \
  {                                                                             \
    f32x4 a0k0 = DSR(LA, AO(qm, 0, 0)), a0k1 = DSR(LA, AO(qm, 0, 1));           \
    f32x4 a1k0 = DSR(LA, AO(qm, 1, 0)), a1k1 = DSR(LA, AO(qm, 1, 1));           \
    f32x4 a2k0 = DSR(LA, AO(qm, 2, 0)), a2k1 = DSR(LA, AO(qm, 2, 1));           \
    f32x4 a3k0 = DSR(LA, AO(qm, 3, 0)), a3k1 = DSR(LA, AO(qm, 3, 1));           \
    f32x4 b0k0 = DSR(LB, BO(qn, 0, 0)), b0k1 = DSR(LB, BO(qn, 0, 1));           \
    f32x4 b1k0 = DSR(LB, BO(qn, 1, 0)), b1k1 = DSR(LB, BO(qn, 1, 1));           \
    STGS                                                                        \
    BAR();                                                                      \
    WAITLGKM();                                                                 \
    SCHEDB();                                                                   \
    PRIO(1);                                                                    \
    MM(qm, 0, qn, 0, a0k0, b0k0) MM(qm, 0, qn, 1, a0k0, b1k0)                   \
    MM(qm, 1, qn, 0, a1k0, b0k0) MM(qm, 1, qn, 1, a1k0, b1k0)                   \
    MM(qm, 2, qn, 0, a2k0, b0k0) MM(qm, 2, qn, 1, a2k0, b1k0)                   \
    MM(qm, 3, qn, 0, a3k0, b0k0) MM(qm, 3, qn, 1, a3k0, b1k0)                   \
    MM(qm, 0, qn, 0, a0k1, b0k1) MM(qm, 0, qn, 1, a0k1, b1k1)                   \
    MM(qm, 1, qn, 0, a1k1, b0k1) MM(qm, 1, qn, 1, a1k1, b1k1)                   \
    MM(qm, 2, qn, 0, a2k1, b0k1) MM(qm, 2, qn, 1, a2k1, b1k1)                   \
    MM(qm, 3, qn, 0, a3k1, b0k1) MM(qm, 3, qn, 1, a3k1, b1k1)                   \
    PRIO(0);                                                                    \
    SCHEDB();                                                                   \
    TAILW                                                                       \
    BAR();                                                                      \
  }

template <typename OT, int EPI>
__global__ __launch_bounds__(512, 2) void gemm256(
    const u16* __restrict__ A, int lda, long zsA,
    const u16* __restrict__ B, int ldb, long zsB,
    OT* __restrict__ C, int ldc, long zsC,
    int K, float scale, const float* __restrict__ rs) {
  __shared__ __align__(16) u16 lds[65536];  // 128 KiB: [buf][A|B][16 rb][2 kb][512]
  const int z = blockIdx.z;
  A += (long)z * zsA;
  B += (long)z * zsB;
  C += (long)z * zsC;
  if constexpr (EPI == 2) rs += (long)z * 4096;

  const int tid  = threadIdx.x;
  const int lane = tid & 63;
  const int w    = tid >> 6;    // wave 0..7
  const int wm   = w >> 2;      // 0..1  (M)
  const int wn   = w & 3;       // 0..3  (N)
  const int wm8  = wm * 8;
  const int wn4  = wn * 4;
  const int l15  = lane & 15;
  const int quad = lane >> 4;
  const int m0   = blockIdx.y * 256;
  const int n0   = blockIdx.x * 256;

  // Staging geometry (R1/R2-verified numerically, zero bank conflicts): wave w
  // owns subtile (rowblock w>>1, kblock w&1); lane l -> row l>>2, k (l&3)*8,
  // with the k pre-XOR implementing the st_16x32 swizzle (rule #21).
  const int srow = (w >> 1) * 16 + (lane >> 2);
  const int kcol = ((lane & 3) * 8) ^ ((lane & 32) ? 16 : 0);
  const int skb  = w & 1;
  const u16* gAs = A + (size_t)(m0 + srow) * lda + skb * 32 + kcol;
  const u16* gBs = B + (size_t)(n0 + srow) * ldb + skb * 32 + kcol;
  const int wsub = (w >> 1) * 2 + skb;

  // Fragment read bases (u16 units), swizzled; per-phase offsets are
  // compile-time immediates on top of these.
  const int rq = (l15 * 32 + quad * 8) ^ ((l15 & 8) << 1);
  const lds_cu16* Lp  = (const lds_cu16*)lds;
  const lds_cu16* LA0 = Lp + wm8 * 1024 + rq;
  const lds_cu16* LA1 = LA0 + 32768;
  const lds_cu16* LB0 = Lp + 16384 + wn4 * 1024 + rq;
  const lds_cu16* LB1 = LB0 + 32768;

  f32x4 acc[8][4];
#pragma unroll
  for (int i = 0; i < 8; ++i)
#pragma unroll
    for (int j = 0; j < 4; ++j) acc[i][j] = f32x4{0.f, 0.f, 0.f, 0.f};

  const int ni = K >> 7;  // iterations of 2 K-tiles (K % 128 == 0)

  // Prologue: tile0 -> buf0 only (t1 is staged inside ph1-2 of iter 0).
#pragma unroll
  for (int h = 0; h < 4; ++h) { STG(0, h, 0, 0); STG(0, h, 1, 0); }
  WAITV(0);
  BAR();

  for (int i = 0; i < ni; ++i) {
    const int t1 = 2 * i + 1, t2 = 2 * i + 2;
    const bool more = (i + 1 < ni);

    // ph1: read buf0 q(0,0) | stage t1 -> buf1 A-half
    PH(LA0, LB0, 0, 0,
       STG(1, 0, 0, t1); STG(1, 0, 1, t1); STG(1, 1, 0, t1); STG(1, 1, 1, t1);, )
    // ph2: read buf0 q(0,1) | stage t1 -> buf1 B-half
    PH(LA0, LB0, 0, 1,
       STG(1, 2, 0, t1); STG(1, 2, 1, t1); STG(1, 3, 0, t1); STG(1, 3, 1, t1);, )
    // ph3: read buf0 q(1,0)
    PH(LA0, LB0, 1, 0, , )
    // ph4: read buf0 q(1,1) | drain t1 (2-3 phase lead) before ph5 reads buf1
    PH(LA0, LB0, 1, 1, , WAITV(0);)
    // ph5: read buf1 q(0,0) | stage t2 -> buf0 A-half
    PH(LA1, LB1, 0, 0,
       if (more) { STG(0, 0, 0, t2); STG(0, 0, 1, t2);
                   STG(0, 1, 0, t2); STG(0, 1, 1, t2); }, )
    // ph6: read buf1 q(0,1) | stage t2 -> buf0 B-half
    PH(LA1, LB1, 0, 1,
       if (more) { STG(0, 2, 0, t2); STG(0, 2, 1, t2);
                   STG(0, 3, 0, t2); STG(0, 3, 1, t2); }, )
    // ph7: read buf1 q(1,0)
    PH(LA1, LB1, 1, 0, , )
    // ph8: read buf1 q(1,1) | drain t2 before next-iter ph1 reads buf0
    PH(LA1, LB1, 1, 1, , WAITV(0);)
  }

  // Epilogue. C/D layout (m89-verified): col = lane&15, row = (lane>>4)*4 + reg
#pragma unroll
  for (int i = 0; i < 8; ++i) {
#pragma unroll
    for (int r = 0; r < 4; ++r) {
      const int row = m0 + wm * 128 + i * 16 + quad * 4 + r;
      float mul = scale;
      if constexpr (EPI == 2) mul = scale / rs[row];
      const size_t ro = (size_t)row * ldc;
#pragma unroll
      for (int j = 0; j < 4; ++j) {
        float v = acc[i][j][r] * mul;
        if constexpr (EPI == 1) v = __expf(v);
        const int col = n0 + wn * 64 + j * 16 + l15;
        if constexpr (__is_same(OT, float))
          C[ro + col] = v;
        else
          C[ro + col] = f2bf(v);
      }
    }
  }
}

// rs[z*4096+row] = sum over 4096 cols of P[z][row][*] (bf16). Direct write.
__global__ __launch_bounds__(256) void rowsum_rows(
    const u16* __restrict__ P, long zsP, float* __restrict__ rs) {
  const int row = blockIdx.x;
  const int z   = blockIdx.y;
  const u16* p = P + (long)z * zsP + (size_t)row * 4096;
  const int tid  = threadIdx.x;
  const int lane = tid & 63;
  const int wave = tid >> 6;

  u16x8 h0 = *(const u16x8*)(p + tid * 16);
  u16x8 h1 = *(const u16x8*)(p + tid * 16 + 8);
  float s = 0.f;
#pragma unroll
  for (int j = 0; j < 8; ++j) s += bf2f(h0[j]) + bf2f(h1[j]);
  for (int o = 32; o > 0; o >>= 1) s += __shfl_xor(s, o, 64);
  __shared__ float red[4];
  if (lane == 0) red[wave] = s;
  __syncthreads();
  if (tid == 0) rs[(size_t)z * 4096 + row] = red[0] + red[1] + red[2] + red[3];
}

// Vt[z][d, s] = V[z][s, d].
__global__ __launch_bounds__(256) void transpose_v(
    const u16* __restrict__ V, int ldv, long zsV,
    u16* __restrict__ Vt, int ldt, long zsT) {
  const int z = blockIdx.z;
  V  += (long)z * zsV;
  Vt += (long)z * zsT;
  __shared__ u16 T[64][65];
  const int d0 = blockIdx.x * 64;
  const int s0 = blockIdx.y * 64;
  const int tid = threadIdx.x;
  const int c = tid & 63;
  const int rbase = (tid >> 6) * 16;
#pragma unroll
  for (int r = 0; r < 16; ++r)
    T[rbase + r][c] = V[(size_t)(s0 + rbase + r) * ldv + d0 + c];
  __syncthreads();
#pragma unroll
  for (int r = 0; r < 16; ++r)
    Vt[(size_t)(d0 + rbase + r) * ldt + s0 + c] = T[c][rbase + r];
}

extern "C" void kernel_launch(void* const* d_in, const int* in_sizes, int n_in,
                              void* d_out, int out_size, void* d_ws, size_t ws_size,
                              hipStream_t stream) {
  const float* x    = (const float*)d_in[0];  // [B*S, D] fp32
  const float* Wqkv = (const float*)d_in[1];  // [3D, D]  fp32
  const float* Wo   = (const float*)d_in[2];  // [D, D]   fp32
  float* out = (float*)d_out;                 // [B*S, D] fp32

  const int Bn = 4, S = 4096, D = 1024;
  const int M = Bn * S;  // 16384
  const int E = 3 * D;   // 3072
  const long SE = (long)S * E, SS = (long)S * S, DS = (long)D * S, SD = (long)S * D;

  const int nz = (ws_size >= (size_t)226492416) ? 2 : 1;  // 216 MB

  char* ws = (char*)d_ws;
  size_t off = 0;
  u16* qkv = (u16*)(ws + off);  off += (size_t)M * E * 2;        // 96 MB
  u16* Sb  = (u16*)(ws + off);  off += (size_t)nz * S * S * 2;   // nz*32 MB
  u16* Vt  = (u16*)(ws + off);  off += (size_t)nz * D * S * 2;   // nz*8 MB
  u16* xb  = (u16*)(ws + off);  off += (size_t)M * D * 2;        // 32 MB
  u16* attn = xb;                 // xb dead after QKV proj
  u16* Wqkvb = (u16*)(ws + off); off += (size_t)E * D * 2;       // 6 MB
  u16* Wob   = (u16*)(ws + off); off += (size_t)D * D * 2;       // 2 MB
  float* rs = (float*)Wqkvb;      // aliases Wqkvb (dead after QKV gemm)

  // 0) fp32 -> bf16 converts (fused)
  const int n1 = M * D / 8, n2 = E * D / 8, n3 = D * D / 8;
  cvt_all<<<(n1 + n2 + n3 + 255) / 256, 256, 0, stream>>>(
      x, Wqkv, Wo, xb, Wqkvb, Wob, n1, n2, n3);

  // 1) QKV projection: qkv = xb @ Wqkvb^T   [16384 x 3072], 12x64 = 768 blocks
  gemm256<u16, 0><<<dim3(E / 256, M / 256, 1), 512, 0, stream>>>(
      xb, D, 0, Wqkvb, D, 0, qkv, E, 0, D, 1.0f, nullptr);

  const float scl = 0.03125f;  // 1/sqrt(1024)
  for (int c = 0; c < Bn; c += nz) {
    const u16* Qc = qkv + (size_t)c * SE;
    transpose_v<<<dim3(D / 64, S / 64, nz), 256, 0, stream>>>(
        Qc + 2 * D, E, SE, Vt, S, DS);
    // QK^T with exp epilogue: 16x16xnz blocks (512 @ nz=2)
    gemm256<u16, 1><<<dim3(S / 256, S / 256, nz), 512, 0, stream>>>(
        Qc, E, SE, Qc + D, E, SE, Sb, S, SS, D, scl, nullptr);
    rowsum_rows<<<dim3(S, nz), 256, 0, stream>>>(Sb, SS, rs);
    // PV stays on 128^2 kernel: 256-tile grid would be only 128 blocks.
    gemm_bt<u16, 2><<<dim3(D / 128, S / 128, nz), 256, 0, stream>>>(
        Sb, S, SS, Vt, S, DS, attn + (size_t)c * SD, D, SD, S, 1.0f, rs);
  }

  // 2) out = attn @ Wo^T  [16384 x 1024] -> fp32, 4x64 = 256 blocks
  gemm256<float, 0><<<dim3(D / 256, M / 256, 1), 512, 0, stream>>>(
      attn, D, 0, Wob, D, 0, out, D, 0, D, 1.0f, nullptr);
}

// Round 5
// 628.633 us; speedup vs baseline: 1.1700x; 1.0018x over previous
//
#include <hip/hip_runtime.h>
#include <hip/hip_bf16.h>
#include <stdint.h>

typedef unsigned short u16;
typedef __bf16 bf16x8 __attribute__((ext_vector_type(8)));
typedef unsigned short u16x8 __attribute__((ext_vector_type(8)));
typedef float f32x4 __attribute__((ext_vector_type(4)));

__device__ __forceinline__ float bf2f(u16 h) {
  union { uint32_t u; float f; } x;
  x.u = ((uint32_t)h) << 16;
  return x.f;
}
__device__ __forceinline__ u16 f2bf(float f) {
  union { float f; uint32_t u; } x;
  x.f = f;
  uint32_t r = x.u + 0x7FFFu + ((x.u >> 16) & 1u);  // round-to-nearest-even
  return (u16)(r >> 16);
}

// async global->LDS, 16B per lane. LDS dest must be wave-uniform base + lane*16.
__device__ __forceinline__ void gload_lds16(const u16* g, u16* l) {
  __builtin_amdgcn_global_load_lds(
      (const __attribute__((address_space(1))) uint32_t*)g,
      (__attribute__((address_space(3))) uint32_t*)l, 16, 0, 0);
}

// Inline-asm LDS read with compile-time byte offset. Opaque to the memory
// legalizer -> no auto vmcnt(0) drain vs in-flight global_load_lds. Completion
// via s_waitcnt lgkmcnt(0) + sched_barrier(0) (rule #18). No "memory"
// clobbers (R2 lesson). volatile keeps re-reads from being CSE'd across
// staging barriers.
typedef __attribute__((address_space(3))) const u16 lds_cu16;
template <int OFF>
__device__ __forceinline__ f32x4 ds_read128o(const lds_cu16* p) {
  f32x4 r;
  asm volatile("ds_read_b128 %0, %1 offset:%2" : "=v"(r) : "v"(p), "n"(OFF));
  return r;
}

// One fused fp32->bf16 convert for x, W_qkv, W_o. Counts are 8-elem chunks.
__global__ __launch_bounds__(256) void cvt_all(
    const float* __restrict__ x, const float* __restrict__ w1,
    const float* __restrict__ w2, u16* __restrict__ xb,
    u16* __restrict__ w1b, u16* __restrict__ w2b, int n1, int n2, int n3) {
  int i = blockIdx.x * 256 + threadIdx.x;
  const float* src;
  u16* dst;
  int j = i;
  if (i < n1) { src = x; dst = xb; }
  else if (i < n1 + n2) { src = w1; dst = w1b; j = i - n1; }
  else if (i < n1 + n2 + n3) { src = w2; dst = w2b; j = i - n1 - n2; }
  else return;
  const float4* p = (const float4*)src + (size_t)j * 2;
  float4 a = p[0], b = p[1];
  u16x8 o;
  o[0] = f2bf(a.x); o[1] = f2bf(a.y); o[2] = f2bf(a.z); o[3] = f2bf(a.w);
  o[4] = f2bf(b.x); o[5] = f2bf(b.y); o[6] = f2bf(b.z); o[7] = f2bf(b.w);
  ((u16x8*)dst)[j] = o;
}

// ---------------------------------------------------------------------------
// OLD 128x128 gemm (m97 structure). Kept ONLY for PV (EPI=2). Proven correct.
// ---------------------------------------------------------------------------
template <typename OT, int EPI>
__global__ __launch_bounds__(256) void gemm_bt(
    const u16* __restrict__ A, int lda, long zsA,
    const u16* __restrict__ B, int ldb, long zsB,
    OT* __restrict__ C, int ldc, long zsC,
    int K, float scale, const float* __restrict__ rs) {
  const int z = blockIdx.z;
  A += (long)z * zsA;
  B += (long)z * zsB;
  C += (long)z * zsC;
  if constexpr (EPI == 2) rs += (long)z * 4096;

  __shared__ __align__(16) u16 As[2 * 128 * 32];
  __shared__ __align__(16) u16 Bs[2 * 128 * 32];
  const int tid  = threadIdx.x;
  const int m0   = blockIdx.y * 128;
  const int n0   = blockIdx.x * 128;
  const int wave = tid >> 6;
  const int lane = tid & 63;
  const int wm   = (wave >> 1) * 64;
  const int wn   = (wave & 1) * 64;
  const int l15  = lane & 15;
  const int quad = lane >> 4;

  f32x4 acc[4][4];
#pragma unroll
  for (int i = 0; i < 4; ++i)
#pragma unroll
    for (int j = 0; j < 4; ++j) acc[i][j] = f32x4{0.f, 0.f, 0.f, 0.f};

  const u16* gA0 = A + (size_t)(m0 + (tid >> 2)) * lda + (tid & 3) * 8;
  const u16* gA1 = A + (size_t)(m0 + 64 + (tid >> 2)) * lda + (tid & 3) * 8;
  const u16* gB0 = B + (size_t)(n0 + (tid >> 2)) * ldb + (tid & 3) * 8;
  const u16* gB1 = B + (size_t)(n0 + 64 + (tid >> 2)) * ldb + (tid & 3) * 8;
  u16* lA0 = As + tid * 8;
  u16* lA1 = As + (256 + tid) * 8;
  u16* lB0 = Bs + tid * 8;
  u16* lB1 = Bs + (256 + tid) * 8;

  for (int k0 = 0; k0 < K; k0 += 64) {
    __syncthreads();
#pragma unroll
    for (int s = 0; s < 2; ++s) {
      gload_lds16(gA0 + k0 + s * 32, lA0 + s * 4096);
      gload_lds16(gA1 + k0 + s * 32, lA1 + s * 4096);
      gload_lds16(gB0 + k0 + s * 32, lB0 + s * 4096);
      gload_lds16(gB1 + k0 + s * 32, lB1 + s * 4096);
    }
    __syncthreads();

#pragma unroll
    for (int s = 0; s < 2; ++s) {
      u16x8 a[4], b[4];
#pragma unroll
      for (int i = 0; i < 4; ++i)
        a[i] = *(const u16x8*)(As + s * 4096 + (wm + i * 16 + l15) * 32 + quad * 8);
#pragma unroll
      for (int j = 0; j < 4; ++j)
        b[j] = *(const u16x8*)(Bs + s * 4096 + (wn + j * 16 + l15) * 32 + quad * 8);
#pragma unroll
      for (int i = 0; i < 4; ++i)
#pragma unroll
        for (int j = 0; j < 4; ++j)
          acc[i][j] = __builtin_amdgcn_mfma_f32_16x16x32_bf16(
              __builtin_bit_cast(bf16x8, a[i]), __builtin_bit_cast(bf16x8, b[j]),
              acc[i][j], 0, 0, 0);
    }
  }

#pragma unroll
  for (int i = 0; i < 4; ++i) {
#pragma unroll
    for (int r = 0; r < 4; ++r) {
      const int row = m0 + wm + i * 16 + quad * 4 + r;
      float mul = scale;
      if constexpr (EPI == 2) mul = scale / rs[row];
      const size_t ro = (size_t)row * ldc;
#pragma unroll
      for (int j = 0; j < 4; ++j) {
        float v = acc[i][j][r] * mul;
        if constexpr (EPI == 1) v = __expf(v);
        const int col = n0 + wn + j * 16 + l15;
        if constexpr (__is_same(OT, float))
          C[ro + col] = v;
        else
          C[ro + col] = f2bf(v);
      }
    }
  }
}

// ---------------------------------------------------------------------------
// 256x256 8-phase GEMM, R5: uniform 2-load/phase staging + counted vmcnt(6)
// (never 0 in steady state) -- T4 discipline per m201/m218.
//
// Geometry: 512 thr = 8 waves (2M x 4N). Contiguous-half quadrant remap:
//   A0 = rows 0-127 (STG h=0), A1 = rows 128-255 (h=1), B0 = cols 0-127
//   (h=2), B1 = cols 128-255 (h=3). Wave (wm,wn): qm rows = qm*128+wm*64,
//   qn cols = qn*128+wn*32. Phase reads: ph1 A0+B0 (12 ds_read), ph2 B1 (4),
//   ph3 A1+B0-reread (12), ph4 none; ph5-8 mirror on buf1. Frags held in
//   regs across phases (peak 16 f32x4 = 64 VGPR).
//
// Stage schedule (1 unit = 2 gload_lds / phase), tiles: even->buf0, odd->buf1:
//   ph1: t1.A1   ph2: t2.A0   ph3: t2.B1   ph4: t2.B0
//   ph5: t2.A1   ph6: t3.A0   ph7: t3.B1   ph8: t3.B0
// Every stage targets a region whose LDS reads ended >=1 phase earlier
// (in-phase read/write regions disjoint in all 8 phases).
// vmcnt(6) at EVERY phase end retires exactly one unit, each first read
// >=4 phases later (FIFO trace in comments below); the waited-on load is
// 3 phases (~900cyc) old => ~no stall. Prologue: t0 all + t1.{A0,B1,B0}
// (14 loads), vmcnt(6) -> t0 landed, steady-state invariant [A0,B1,B0] in
// flight. Last iteration peeled with tapering waits 6/4/2/0.
// ---------------------------------------------------------------------------
#define BAR() __builtin_amdgcn_s_barrier()
#define PRIO(n) __builtin_amdgcn_s_setprio(n)
#define WAITV(n) asm volatile("s_waitcnt vmcnt(" #n ")")
#define WAITLGKM() asm volatile("s_waitcnt lgkmcnt(0)")
#define SCHEDB() __builtin_amdgcn_sched_barrier(0)

#define STG(c, h, q, t)                                                         \
  gload_lds16(((h) < 2 ? gAs : gBs) +                                           \
                  (size_t)(((h) & 1) * 128 + (q) * 64) * ((h) < 2 ? lda : ldb) + \
                  (size_t)(t) * 64,                                             \
              lds + (c) * 32768 + ((h) < 2 ? 0 : 16384) +                       \
                  (((h) & 1) * 8 + (q) * 4) * 1024 + wsub * 512)

// 8 A-frag reads (4 rowblocks x 2 k-halves). RB8 = qm*8 (literal).
#define RDA(dst, base, RB8)                                                     \
  dst[0] = ds_read128o<(((RB8) + 0) * 2048 + 0)>(base);                         \
  dst[1] = ds_read128o<(((RB8) + 0) * 2048 + 1024)>(base);                      \
  dst[2] = ds_read128o<(((RB8) + 1) * 2048 + 0)>(base);                         \
  dst[3] = ds_read128o<(((RB8) + 1) * 2048 + 1024)>(base);                      \
  dst[4] = ds_read128o<(((RB8) + 2) * 2048 + 0)>(base);                         \
  dst[5] = ds_read128o<(((RB8) + 2) * 2048 + 1024)>(base);                      \
  dst[6] = ds_read128o<(((RB8) + 3) * 2048 + 0)>(base);                         \
  dst[7] = ds_read128o<(((RB8) + 3) * 2048 + 1024)>(base);

// 4 B-frag reads (2 rowblocks x 2 k-halves). RB8 = qn*8 (literal).
#define RDB(dst, base, RB8)                                                     \
  dst[0] = ds_read128o<(((RB8) + 0) * 2048 + 0)>(base);                         \
  dst[1] = ds_read128o<(((RB8) + 0) * 2048 + 1024)>(base);                      \
  dst[2] = ds_read128o<(((RB8) + 1) * 2048 + 0)>(base);                         \
  dst[3] = ds_read128o<(((RB8) + 1) * 2048 + 1024)>(base);

#define MM1(i, j, AV, BV)                                                       \
  acc[i][j] = __builtin_amdgcn_mfma_f32_16x16x32_bf16(                          \
      __builtin_bit_cast(bf16x8, AV), __builtin_bit_cast(bf16x8, BV),           \
      acc[i][j], 0, 0, 0);

// 16 MFMA: quadrant (qm,qn), FA[ii*2+kk], FB[jj*2+kk], kk-major for ILP.
#define MFMA16(qm, qn, FA, FB)                                                  \
  PRIO(1);                                                                      \
  MM1((qm)*4+0, (qn)*2+0, FA[0], FB[0]) MM1((qm)*4+0, (qn)*2+1, FA[0], FB[2])   \
  MM1((qm)*4+1, (qn)*2+0, FA[2], FB[0]) MM1((qm)*4+1, (qn)*2+1, FA[2], FB[2])   \
  MM1((qm)*4+2, (qn)*2+0, FA[4], FB[0]) MM1((qm)*4+2, (qn)*2+1, FA[4], FB[2])   \
  MM1((qm)*4+3, (qn)*2+0, FA[6], FB[0]) MM1((qm)*4+3, (qn)*2+1, FA[6], FB[2])   \
  MM1((qm)*4+0, (qn)*2+0, FA[1], FB[1]) MM1((qm)*4+0, (qn)*2+1, FA[1], FB[3])   \
  MM1((qm)*4+1, (qn)*2+0, FA[3], FB[1]) MM1((qm)*4+1, (qn)*2+1, FA[3], FB[3])   \
  MM1((qm)*4+2, (qn)*2+0, FA[5], FB[1]) MM1((qm)*4+2, (qn)*2+1, FA[5], FB[3])   \
  MM1((qm)*4+3, (qn)*2+0, FA[7], FB[1]) MM1((qm)*4+3, (qn)*2+1, FA[7], FB[3])   \
  PRIO(0);

#define PH_MID() SCHEDB(); BAR(); WAITLGKM(); SCHEDB()

template <typename OT, int EPI>
__global__ __launch_bounds__(512, 2) void gemm256(
    const u16* __restrict__ A, int lda, long zsA,
    const u16* __restrict__ B, int ldb, long zsB,
    OT* __restrict__ C, int ldc, long zsC,
    int K, float scale, const float* __restrict__ rs) {
  __shared__ __align__(16) u16 lds[65536];  // 128 KiB: [buf][A|B][16 rb][2 kb][512]
  const int z = blockIdx.z;
  A += (long)z * zsA;
  B += (long)z * zsB;
  C += (long)z * zsC;
  if constexpr (EPI == 2) rs += (long)z * 4096;

  const int tid  = threadIdx.x;
  const int lane = tid & 63;
  const int w    = tid >> 6;    // wave 0..7
  const int wm   = w >> 2;      // 0..1  (M)
  const int wn   = w & 3;       // 0..3  (N)
  const int l15  = lane & 15;
  const int quad = lane >> 4;
  const int m0   = blockIdx.y * 256;
  const int n0   = blockIdx.x * 256;

  // Staging geometry (R1/R2/R4-verified, zero bank conflicts): wave w owns
  // subtile (rowblock w>>1, kblock w&1); lane l -> row l>>2, k (l&3)*8, with
  // the k pre-XOR implementing the st_16x32 swizzle (rule #21).
  const int srow = (w >> 1) * 16 + (lane >> 2);
  const int kcol = ((lane & 3) * 8) ^ ((lane & 32) ? 16 : 0);
  const int skb  = w & 1;
  const u16* gAs = A + (size_t)(m0 + srow) * lda + skb * 32 + kcol;
  const u16* gBs = B + (size_t)(n0 + srow) * ldb + skb * 32 + kcol;
  const int wsub = (w >> 1) * 2 + skb;

  // Fragment read bases (u16 units), swizzled; per-phase rowblock offsets are
  // compile-time immediates. A rb = qm*8 + wm*4 + ii; B rb = qn*8 + wn*2 + jj.
  const int rq = (l15 * 32 + quad * 8) ^ ((l15 & 8) << 1);
  const lds_cu16* Lp  = (const lds_cu16*)lds;
  const lds_cu16* LA0 = Lp + wm * 4 * 1024 + rq;
  const lds_cu16* LA1 = LA0 + 32768;
  const lds_cu16* LB0 = Lp + 16384 + wn * 2 * 1024 + rq;
  const lds_cu16* LB1 = LB0 + 32768;

  f32x4 acc[8][4];
#pragma unroll
  for (int i = 0; i < 8; ++i)
#pragma unroll
    for (int j = 0; j < 4; ++j) acc[i][j] = f32x4{0.f, 0.f, 0.f, 0.f};
  f32x4 fA0[8], fA1[8], fB0[4], fB1[4];

  const int ni = K >> 7;  // 2-K-tile iterations; all callers use K=1024 (ni=8)

  // Prologue: t0 fully (8 loads), then t1.{A0,B1,B0} in FIFO order matching
  // the steady-state invariant. vmcnt(6): t0 landed, t1's 6 in flight.
  STG(0, 0, 0, 0); STG(0, 0, 1, 0);  // t0.A0
  STG(0, 2, 0, 0); STG(0, 2, 1, 0);  // t0.B0
  STG(0, 3, 0, 0); STG(0, 3, 1, 0);  // t0.B1
  STG(0, 1, 0, 0); STG(0, 1, 1, 0);  // t0.A1
  STG(1, 0, 0, 1); STG(1, 0, 1, 1);  // t1.A0
  STG(1, 3, 0, 1); STG(1, 3, 1, 1);  // t1.B1
  STG(1, 2, 0, 1); STG(1, 2, 1, 1);  // t1.B0
  WAITV(6);
  BAR();

  for (int i = 0; i < ni - 1; ++i) {
    const int t1 = 2 * i + 1, t2 = 2 * i + 2, t3 = 2 * i + 3;
    // ph1: read buf0.{A0,B0} | stage t1.A1->buf1.A1 | mfma(0,0) | vm6: t1.A0
    RDA(fA0, LA0, 0) RDB(fB0, LB0, 0)
    STG(1, 1, 0, t1); STG(1, 1, 1, t1);
    PH_MID(); MFMA16(0, 0, fA0, fB0) SCHEDB(); WAITV(6); BAR();
    // ph2: read buf0.B1 | stage t2.A0->buf0.A0 | mfma(0,1) | vm6: t1.B1
    RDB(fB1, LB0, 8)
    STG(0, 0, 0, t2); STG(0, 0, 1, t2);
    PH_MID(); MFMA16(0, 1, fA0, fB1) SCHEDB(); WAITV(6); BAR();
    // ph3: read buf0.{A1,B0} | stage t2.B1->buf0.B1 | mfma(1,0) | vm6: t1.B0
    RDA(fA1, LA0, 8) RDB(fB0, LB0, 0)
    STG(0, 3, 0, t2); STG(0, 3, 1, t2);
    PH_MID(); MFMA16(1, 0, fA1, fB0) SCHEDB(); WAITV(6); BAR();
    // ph4: no reads | stage t2.B0->buf0.B0 | mfma(1,1) | vm6: t1.A1
    STG(0, 2, 0, t2); STG(0, 2, 1, t2);
    SCHEDB(); BAR(); SCHEDB(); MFMA16(1, 1, fA1, fB1) SCHEDB(); WAITV(6); BAR();
    // ph5: read buf1.{A0,B0} | stage t2.A1->buf0.A1 | mfma(0,0) | vm6: t2.A0
    RDA(fA0, LA1, 0) RDB(fB0, LB1, 0)
    STG(0, 1, 0, t2); STG(0, 1, 1, t2);
    PH_MID(); MFMA16(0, 0, fA0, fB0) SCHEDB(); WAITV(6); BAR();
    // ph6: read buf1.B1 | stage t3.A0->buf1.A0 | mfma(0,1) | vm6: t2.B1
    RDB(fB1, LB1, 8)
    STG(1, 0, 0, t3); STG(1, 0, 1, t3);
    PH_MID(); MFMA16(0, 1, fA0, fB1) SCHEDB(); WAITV(6); BAR();
    // ph7: read buf1.{A1,B0} | stage t3.B1->buf1.B1 | mfma(1,0) | vm6: t2.B0
    RDA(fA1, LA1, 8) RDB(fB0, LB1, 0)
    STG(1, 3, 0, t3); STG(1, 3, 1, t3);
    PH_MID(); MFMA16(1, 0, fA1, fB0) SCHEDB(); WAITV(6); BAR();
    // ph8: no reads | stage t3.B0->buf1.B0 | mfma(1,1) | vm6: t2.A1
    STG(1, 2, 0, t3); STG(1, 2, 1, t3);
    SCHEDB(); BAR(); SCHEDB(); MFMA16(1, 1, fA1, fB1) SCHEDB(); WAITV(6); BAR();
  }

  // Peeled last iteration: only t1.A1 staged; tapering waits 6/4/2/0.
  {
    const int t1 = 2 * ni - 1;
    RDA(fA0, LA0, 0) RDB(fB0, LB0, 0)
    STG(1, 1, 0, t1); STG(1, 1, 1, t1);
    PH_MID(); MFMA16(0, 0, fA0, fB0) SCHEDB(); WAITV(6); BAR();  // tL.A0 landed
    RDB(fB1, LB0, 8)
    PH_MID(); MFMA16(0, 1, fA0, fB1) SCHEDB(); WAITV(4); BAR();  // tL.B1
    RDA(fA1, LA0, 8) RDB(fB0, LB0, 0)
    PH_MID(); MFMA16(1, 0, fA1, fB0) SCHEDB(); WAITV(2); BAR();  // tL.B0
    SCHEDB(); BAR(); SCHEDB(); MFMA16(1, 1, fA1, fB1) SCHEDB(); WAITV(0); BAR();
    RDA(fA0, LA1, 0) RDB(fB0, LB1, 0)
    PH_MID(); MFMA16(0, 0, fA0, fB0) SCHEDB(); BAR();
    RDB(fB1, LB1, 8)
    PH_MID(); MFMA16(0, 1, fA0, fB1) SCHEDB(); BAR();
    RDA(fA1, LA1, 8) RDB(fB0, LB1, 0)
    PH_MID(); MFMA16(1, 0, fA1, fB0) SCHEDB(); BAR();
    WAITLGKM(); SCHEDB(); MFMA16(1, 1, fA1, fB1)
  }

  // Epilogue. Quadrant remap: acc[i][j] -> row m0 + (i>>2)*128 + wm*64 +
  // (i&3)*16 + quad*4 + r; col n0 + (j>>1)*128 + wn*32 + (j&1)*16 + l15.
#pragma unroll
  for (int i = 0; i < 8; ++i) {
#pragma unroll
    for (int r = 0; r < 4; ++r) {
      const int row = m0 + (i >> 2) * 128 + wm * 64 + (i & 3) * 16 + quad * 4 + r;
      float mul = scale;
      if constexpr (EPI == 2) mul = scale / rs[row];
      const size_t ro = (size_t)row * ldc;
#pragma unroll
      for (int j = 0; j < 4; ++j) {
        float v = acc[i][j][r] * mul;
        if constexpr (EPI == 1) v = __expf(v);
        const int col = n0 + (j >> 1) * 128 + wn * 32 + (j & 1) * 16 + l15;
        if constexpr (__is_same(OT, float))
          C[ro + col] = v;
        else
          C[ro + col] = f2bf(v);
      }
    }
  }
}

// rs[z*4096+row] = sum over 4096 cols of P[z][row][*] (bf16). Direct write.
__global__ __launch_bounds__(256) void rowsum_rows(
    const u16* __restrict__ P, long zsP, float* __restrict__ rs) {
  const int row = blockIdx.x;
  const int z   = blockIdx.y;
  const u16* p = P + (long)z * zsP + (size_t)row * 4096;
  const int tid  = threadIdx.x;
  const int lane = tid & 63;
  const int wave = tid >> 6;

  u16x8 h0 = *(const u16x8*)(p + tid * 16);
  u16x8 h1 = *(const u16x8*)(p + tid * 16 + 8);
  float s = 0.f;
#pragma unroll
  for (int j = 0; j < 8; ++j) s += bf2f(h0[j]) + bf2f(h1[j]);
  for (int o = 32; o > 0; o >>= 1) s += __shfl_xor(s, o, 64);
  __shared__ float red[4];
  if (lane == 0) red[wave] = s;
  __syncthreads();
  if (tid == 0) rs[(size_t)z * 4096 + row] = red[0] + red[1] + red[2] + red[3];
}

// Vt[z][d, s] = V[z][s, d].
__global__ __launch_bounds__(256) void transpose_v(
    const u16* __restrict__ V, int ldv, long zsV,
    u16* __restrict__ Vt, int ldt, long zsT) {
  const int z = blockIdx.z;
  V  += (long)z * zsV;
  Vt += (long)z * zsT;
  __shared__ u16 T[64][65];
  const int d0 = blockIdx.x * 64;
  const int s0 = blockIdx.y * 64;
  const int tid = threadIdx.x;
  const int c = tid & 63;
  const int rbase = (tid >> 6) * 16;
#pragma unroll
  for (int r = 0; r < 16; ++r)
    T[rbase + r][c] = V[(size_t)(s0 + rbase + r) * ldv + d0 + c];
  __syncthreads();
#pragma unroll
  for (int r = 0; r < 16; ++r)
    Vt[(size_t)(d0 + rbase + r) * ldt + s0 + c] = T[c][rbase + r];
}

extern "C" void kernel_launch(void* const* d_in, const int* in_sizes, int n_in,
                              void* d_out, int out_size, void* d_ws, size_t ws_size,
                              hipStream_t stream) {
  const float* x    = (const float*)d_in[0];  // [B*S, D] fp32
  const float* Wqkv = (const float*)d_in[1];  // [3D, D]  fp32
  const float* Wo   = (const float*)d_in[2];  // [D, D]   fp32
  float* out = (float*)d_out;                 // [B*S, D] fp32

  const int Bn = 4, S = 4096, D = 1024;
  const int M = Bn * S;  // 16384
  const int E = 3 * D;   // 3072
  const long SE = (long)S * E, SS = (long)S * S, DS = (long)D * S, SD = (long)S * D;

  const int nz = (ws_size >= (size_t)226492416) ? 2 : 1;  // 216 MB

  char* ws = (char*)d_ws;
  size_t off = 0;
  u16* qkv = (u16*)(ws + off);  off += (size_t)M * E * 2;        // 96 MB
  u16* Sb  = (u16*)(ws + off);  off += (size_t)nz * S * S * 2;   // nz*32 MB
  u16* Vt  = (u16*)(ws + off);  off += (size_t)nz * D * S * 2;   // nz*8 MB
  u16* xb  = (u16*)(ws + off);  off += (size_t)M * D * 2;        // 32 MB
  u16* attn = xb;                 // xb dead after QKV proj
  u16* Wqkvb = (u16*)(ws + off); off += (size_t)E * D * 2;       // 6 MB
  u16* Wob   = (u16*)(ws + off); off += (size_t)D * D * 2;       // 2 MB
  float* rs = (float*)Wqkvb;      // aliases Wqkvb (dead after QKV gemm)

  // 0) fp32 -> bf16 converts (fused)
  const int n1 = M * D / 8, n2 = E * D / 8, n3 = D * D / 8;
  cvt_all<<<(n1 + n2 + n3 + 255) / 256, 256, 0, stream>>>(
      x, Wqkv, Wo, xb, Wqkvb, Wob, n1, n2, n3);

  // 1) QKV projection: qkv = xb @ Wqkvb^T   [16384 x 3072], 12x64 = 768 blocks
  gemm256<u16, 0><<<dim3(E / 256, M / 256, 1), 512, 0, stream>>>(
      xb, D, 0, Wqkvb, D, 0, qkv, E, 0, D, 1.0f, nullptr);

  const float scl = 0.03125f;  // 1/sqrt(1024)
  for (int c = 0; c < Bn; c += nz) {
    const u16* Qc = qkv + (size_t)c * SE;
    transpose_v<<<dim3(D / 64, S / 64, nz), 256, 0, stream>>>(
        Qc + 2 * D, E, SE, Vt, S, DS);
    // QK^T with exp epilogue: 16x16xnz blocks (512 @ nz=2)
    gemm256<u16, 1><<<dim3(S / 256, S / 256, nz), 512, 0, stream>>>(
        Qc, E, SE, Qc + D, E, SE, Sb, S, SS, D, scl, nullptr);
    rowsum_rows<<<dim3(S, nz), 256, 0, stream>>>(Sb, SS, rs);
    // PV stays on 128^2 kernel: 256-tile grid would be only 128 blocks.
    gemm_bt<u16, 2><<<dim3(D / 128, S / 128, nz), 256, 0, stream>>>(
        Sb, S, SS, Vt, S, DS, attn + (size_t)c * SD, D, SD, S, 1.0f, rs);
  }

  // 2) out = attn @ Wo^T  [16384 x 1024] -> fp32, 4x64 = 256 blocks
  gemm256<float, 0><<<dim3(D / 256, M / 256, 1), 512, 0, stream>>>(
      attn, D, 0, Wob, D, 0, out, D, 0, D, 1.0f, nullptr);
}